// Round 1
// 77.365 us; speedup vs baseline: 1.2137x; 1.2137x over previous
//
#include <hip/hip_runtime.h>
#include <hip/hip_fp16.h>
#include <hip/hip_bf16.h>

#define TL 3000
#define NN 30000
#define DIM 128
#define KNEG 75
#define NQL (2 * TL)
#define EPSF 1e-7f
#define MAXSQ 50.0f

#define ECAND 128         // gate candidate sample (rows 0..127); was 512
#define QT 64             // query rows per block
#define QBLK 94           // ceil(6000/64)
#define FLAGTH 36         // expected count ~68/128, sigma ~5.7 -> 5.6-sigma margin

typedef __attribute__((ext_vector_type(8))) short bf16x8;
typedef __attribute__((ext_vector_type(4))) float f32x4;

__device__ __forceinline__ int wred_i(int v) {
#pragma unroll
  for (int o = 32; o > 0; o >>= 1) v += __shfl_xor(v, o, 64);
  return v;
}
__device__ __forceinline__ float wred_f(float v) {
#pragma unroll
  for (int o = 32; o > 0; o >>= 1) v += __shfl_xor(v, o, 64);
  return v;
}

__device__ __forceinline__ float sqdist_f(float prod, float cv, float K) {
  float theta = fmaxf(-prod * cv, 1.0f + EPSF);
  float a = acoshf(theta);
  return fminf(K * a * a, MAXSQ);
}

// Pack 8 fp32 -> 8 bf16 by TRUNCATION (top 16 bits), one v_perm_b32 per pair.
// Gate-only precision: threshold margin is ~5 sigma, truncation error irrelevant.
__device__ __forceinline__ bf16x8 pack_hi16(float4 f0, float4 f1) {
  union { bf16x8 v; unsigned int u[4]; } r;
  r.u[0] = __builtin_amdgcn_perm(__float_as_uint(f0.y), __float_as_uint(f0.x), 0x07060302u);
  r.u[1] = __builtin_amdgcn_perm(__float_as_uint(f0.w), __float_as_uint(f0.z), 0x07060302u);
  r.u[2] = __builtin_amdgcn_perm(__float_as_uint(f1.y), __float_as_uint(f1.x), 0x07060302u);
  r.u[3] = __builtin_amdgcn_perm(__float_as_uint(f1.w), __float_as_uint(f1.z), 0x07060302u);
  return r.v;
}

// ---------- gate kernel: MFMA count over 128 sampled candidates + D + closed form ----------
// No LDS staging: each wave loads its own 32 candidate rows directly into B fragments.
__launch_bounds__(256)
__global__ void gate_kernel(const float* __restrict__ emb, const float* __restrict__ c,
                            const int* __restrict__ links, float* __restrict__ partial,
                            int* __restrict__ nf, int* __restrict__ list) {
  __shared__ int lc[QT + 1];  // per-query counts + flag counter
  const int tid = threadIdx.x;
  const int lane = tid & 63;
  const int w = tid >> 6;
  const int am = lane & 15;
  const int aq = lane >> 4;
  const int qt = blockIdx.x;
  const float cv = c[0];
  const float K = 1.0f / cv;
  const float thresh = -(1.0f + EPSF) / cv;

  if (tid <= QT) lc[tid] = 0;

  // A fragments: this block's 64 query rows, truncated to bf16.
  // A[m=lane&15][k = kc*32 + aq*8 + j]; k==0 negated (q'[0] = -q[0]).
  bf16x8 A[4][4];
#pragma unroll
  for (int mg = 0; mg < 4; ++mg) {
    int q = qt * QT + mg * 16 + am;
    int node = 0;
    if (q < NQL) {
      int li = (q < TL) ? q : q - TL;
      node = (q < TL) ? links[2 * li] : links[2 * li + 1];
    }
    const float* qr = emb + (size_t)node * DIM;
#pragma unroll
    for (int kc = 0; kc < 4; ++kc) {
      float4 f0 = *(const float4*)(qr + kc * 32 + aq * 8);
      float4 f1 = *(const float4*)(qr + kc * 32 + aq * 8 + 4);
      if (kc == 0 && aq == 0) f0.x = -f0.x;
      A[mg][kc] = pack_hi16(f0, f1);
    }
  }

  // B fragments: wave w's 32 candidate rows (global rows w*32 .. w*32+31), direct to regs.
  // B[k = kc*32 + aq*8 + j][n = sg*16 + am] -- same per-lane gather pattern as A.
  bf16x8 Bf[2][4];
#pragma unroll
  for (int sgl = 0; sgl < 2; ++sgl) {
    const float* src = emb + (size_t)((w * 2 + sgl) * 16 + am) * DIM;
#pragma unroll
    for (int kc = 0; kc < 4; ++kc) {
      float4 f0 = *(const float4*)(src + kc * 32 + aq * 8);
      float4 f1 = *(const float4*)(src + kc * 32 + aq * 8 + 4);
      Bf[sgl][kc] = pack_hi16(f0, f1);
    }
  }

  // MFMA: 64 queries x 32 candidates per wave; count prod >= thresh per query.
  int cnt[4][4];
#pragma unroll
  for (int mg = 0; mg < 4; ++mg)
#pragma unroll
    for (int r = 0; r < 4; ++r) cnt[mg][r] = 0;
#pragma unroll
  for (int mg = 0; mg < 4; ++mg)
#pragma unroll
    for (int sgl = 0; sgl < 2; ++sgl) {
      f32x4 acc = {0.f, 0.f, 0.f, 0.f};
#pragma unroll
      for (int kc = 0; kc < 4; ++kc)
        acc = __builtin_amdgcn_mfma_f32_16x16x32_bf16(A[mg][kc], Bf[sgl][kc], acc, 0, 0, 0);
#pragma unroll
      for (int r = 0; r < 4; ++r) cnt[mg][r] += (acc[r] >= thresh);
    }

  // D per query (wave 0, one thread per query) -- EXACT same op order as the
  // verified kernel so the closed-form output is bit-identical. Computed before
  // the barrier so its loads overlap other waves' MFMA work.
  float Dq = 0.f;
  int qvalid = 0;
  if (tid < QT) {
    int q = qt * QT + tid;
    if (q < NQL) {
      qvalid = 1;
      int li = (q < TL) ? q : q - TL;
      long l = links[2 * li];
      long r = links[2 * li + 1];
      const float4* x = (const float4*)(emb + l * DIM);
      const float4* y = (const float4*)(emb + r * DIM);
      float dot = 0.f, x0 = 0.f, y0 = 0.f;
#pragma unroll
      for (int k = 0; k < 32; ++k) {
        float4 a = x[k], b = y[k];
        if (k == 0) { x0 = a.x; y0 = b.x; }
        dot = fmaf(a.x, b.x, dot);
        dot = fmaf(a.y, b.y, dot);
        dot = fmaf(a.z, b.z, dot);
        dot = fmaf(a.w, b.w, dot);
      }
      Dq = sqdist_f(dot - 2.0f * x0 * y0, cv, K) + 1.0f;  // + GAMMA
    }
  }

  __syncthreads();  // lc init visible before atomics

  // cross-wave count reduction: sum over am (candidate lanes), atomic per query
#pragma unroll
  for (int mg = 0; mg < 4; ++mg)
#pragma unroll
    for (int r = 0; r < 4; ++r) {
      int v = cnt[mg][r];
      v += __shfl_xor(v, 1, 64);
      v += __shfl_xor(v, 2, 64);
      v += __shfl_xor(v, 4, 64);
      v += __shfl_xor(v, 8, 64);
      if (am == 0) atomicAdd(&lc[mg * 16 + aq * 4 + r], v);
    }
  __syncthreads();

  // finalize: gate decision + closed-form contribution (wave 0)
  if (tid < QT) {
    float contrib = 0.f;
    if (qvalid) {
      float acl = acoshf(1.0f + EPSF);
      float clipv = fminf(K * acl * acl, MAXSQ);
      if (lc[tid] >= FLAGTH) {
        contrib = (float)KNEG * fmaxf(Dq - clipv, 0.f);
      } else {
        int p = atomicAdd(&lc[QT], 1);
        list[qt * QT + p] = qt * QT + tid;
      }
    }
    contrib = wred_f(contrib);
    if (tid == 0) partial[qt] = contrib * (1.0f / (2.0f * (float)KNEG * (float)TL));
  }
  __syncthreads();
  if (tid == 0) nf[qt] = lc[QT];
}

// ---------- final: sum partials; exact fallback only if any query was flagged ----------
__launch_bounds__(256)
__global__ void final_kernel(const float* __restrict__ emb, const float* __restrict__ c,
                             const int* __restrict__ links, const float* __restrict__ partial,
                             const int* __restrict__ nf, const int* __restrict__ list,
                             float* __restrict__ out) {
  __shared__ __align__(16) float qvec[DIM];
  __shared__ unsigned short s16[NN];  // 60000 B
  __shared__ int ish[4];
  __shared__ float fsh[4];
  __shared__ float acc_total;
  const int tid = threadIdx.x;

  // parallel preload of partials AND flag counts
  float t = (tid < QBLK) ? partial[tid] : 0.f;
  int nme = (tid < QBLK) ? nf[tid] : 0;
  t = wred_f(t);
  nme = wred_i(nme);
  if ((tid & 63) == 0) { fsh[tid >> 6] = t; ish[tid >> 6] = nme; }
  __syncthreads();
  if (tid == 0) acc_total = fsh[0] + fsh[1] + fsh[2] + fsh[3];
  int totf = ish[0] + ish[1] + ish[2] + ish[3];
  if (totf == 0) {  // common path: nothing flagged, done
    if (tid == 0) out[0] = acc_total;
    return;
  }
  __syncthreads();

  const float cv = c[0];
  const float K = 1.0f / cv;

  for (int qt = 0; qt < QBLK; ++qt) {
    int n = nf[qt];
    for (int j = 0; j < n; ++j) {
      const int q = list[qt * QT + j];
      const int li = (q < TL) ? q : q - TL;
      const int node = (q < TL) ? links[2 * li] : links[2 * li + 1];

      float Dq;
      {
        long l = links[2 * li];
        long r = links[2 * li + 1];
        const float4* x = (const float4*)(emb + l * DIM);
        const float4* y = (const float4*)(emb + r * DIM);
        float dot = 0.f, x0 = 0.f, y0 = 0.f;
#pragma unroll
        for (int k = 0; k < 32; ++k) {
          float4 a = x[k], b = y[k];
          if (k == 0) { x0 = a.x; y0 = b.x; }
          dot = fmaf(a.x, b.x, dot);
          dot = fmaf(a.y, b.y, dot);
          dot = fmaf(a.z, b.z, dot);
          dot = fmaf(a.w, b.w, dot);
        }
        Dq = sqdist_f(dot - 2.0f * x0 * y0, cv, K) + 1.0f;
      }

      if (tid < DIM) qvec[tid] = emb[(long)node * DIM + tid];
      __syncthreads();
      const float q0 = qvec[0];
      const float4* q4 = (const float4*)qvec;

      for (int jj = tid; jj < NN; jj += 256) {
        const float4* row = (const float4*)(emb + (long)jj * DIM);
        float acc = 0.f, e0 = 0.f;
#pragma unroll
        for (int k = 0; k < DIM / 4; ++k) {
          float4 e = row[k];
          float4 v = q4[k];
          if (k == 0) e0 = e.x;
          acc = fmaf(e.x, v.x, acc);
          acc = fmaf(e.y, v.y, acc);
          acc = fmaf(e.z, v.z, acc);
          acc = fmaf(e.w, v.w, acc);
        }
        float s = sqdist_f(acc - 2.0f * e0 * q0, cv, K);
        s16[jj] = __half_as_ushort(__float2half_rn(s));
      }
      __syncthreads();

      unsigned int lo = 0, hi = 0xFFFFu;
      while (lo < hi) {
        unsigned int mid = (lo + hi) >> 1;
        int cntb = 0;
        for (int jj = tid; jj < NN; jj += 256) cntb += (s16[jj] <= mid) ? 1 : 0;
        cntb = wred_i(cntb);
        if ((tid & 63) == 0) ish[tid >> 6] = cntb;
        __syncthreads();
        int tot = ish[0] + ish[1] + ish[2] + ish[3];
        if (tot >= KNEG) hi = mid; else lo = mid + 1;
        __syncthreads();
      }
      const unsigned int T = lo;
      const float Tval = __half2float(__ushort_as_half((unsigned short)T));

      int nl = 0;
      float sum = 0.f;
      for (int jj = tid; jj < NN; jj += 256) {
        unsigned short kk = s16[jj];
        if ((unsigned int)kk < T) {
          nl++;
          sum += fmaxf(Dq - __half2float(__ushort_as_half(kk)), 0.f);
        }
      }
      nl = wred_i(nl);
      sum = wred_f(sum);
      if ((tid & 63) == 0) { ish[tid >> 6] = nl; fsh[tid >> 6] = sum; }
      __syncthreads();
      if (tid == 0) {
        int n_less = ish[0] + ish[1] + ish[2] + ish[3];
        float s = fsh[0] + fsh[1] + fsh[2] + fsh[3];
        s += (float)(KNEG - n_less) * fmaxf(Dq - Tval, 0.f);
        acc_total += s * (1.0f / (2.0f * (float)KNEG * (float)TL));
      }
      __syncthreads();
    }
  }
  if (tid == 0) out[0] = acc_total;
}

extern "C" void kernel_launch(void* const* d_in, const int* in_sizes, int n_in,
                              void* d_out, int out_size, void* d_ws, size_t ws_size,
                              hipStream_t stream) {
  const float* emb = (const float*)d_in[0];
  const float* c = (const float*)d_in[1];
  const int* links = (const int*)d_in[2];
  float* out = (float*)d_out;

  float* partial = (float*)d_ws;          // 94 floats
  int* nf = (int*)(partial + QBLK);       // 94 ints
  int* list = nf + QBLK;                  // 94*64 ints

  gate_kernel<<<QBLK, 256, 0, stream>>>(emb, c, links, partial, nf, list);
  final_kernel<<<1, 256, 0, stream>>>(emb, c, links, partial, nf, list, out);
}